// Round 11
// baseline (165.232 us; speedup 1.0000x reference)
//
#include <hip/hip_runtime.h>
#include <stdint.h>

#define NQ 8192
#define NK 8192
#define DIN 32

#define BT 256                 // threads per block (4 waves)
#define RPW 2                  // q-rows per wave (2 hash chains)
#define ROWS_PER_BLOCK 8       // 4 waves * RPW

// keep  <=>  (bits >> 9) < 6710887  <=>  bits < 6710887*512  (bit-exact, verified r2-r10)
#define KEEP_BITS 3435974144u
// fold 1/16 (score scale) and log2(e) into q so e = exp2(dot(qs, k))
#define QSCALE 0.09016844005556021f

typedef float f32x2 __attribute__((ext_vector_type(2)));

// ---------------- threefry2x32-20, JAX partitionable path ----------------
// key = jax.random.key(42) -> (0, 42); counter (hi,lo) = (0, flat_idx)
// bits = out0 ^ out1. Bit-exact schedule (verified r2-r10), 2 chains,
// key-injections folded into the next round's x0-add via v_add3_u32.
// rotl(x,r) == v_alignbit_b32(x,x,32-r):
//   rot 13,15,26,6,17,29,16,24 -> S 19,17,6,26,15,3,16,8
// ks1 = 42, ks2 = 0x1BD11BDA ^ 42 = 0x1BD11BF0 (SGPR %4 below)

__device__ __forceinline__ uint32_t rotl(uint32_t v, int d) {
    return __builtin_amdgcn_alignbit(v, v, 32 - d);
}

#define TF_ROUND2(S) \
  "v_add_u32 %0,%0,%2\n v_add_u32 %1,%1,%3\n"                          \
  "v_alignbit_b32 %2,%2,%2," #S "\n v_alignbit_b32 %3,%3,%3," #S "\n"  \
  "v_xor_b32 %2,%2,%0\n v_xor_b32 %3,%3,%1\n"

#define TF_RINJ2(C0, C1, S) \
  "v_add_u32 %2," #C1 ",%2\n v_add_u32 %3," #C1 ",%3\n"                \
  "v_add3_u32 %0,%0," #C0 ",%2\n v_add3_u32 %1,%1," #C0 ",%3\n"        \
  "v_alignbit_b32 %2,%2,%2," #S "\n v_alignbit_b32 %3,%3,%3," #S "\n"  \
  "v_xor_b32 %2,%2,%0\n v_xor_b32 %3,%3,%1\n"

#define TF_RINJS2(C1, S) \
  "v_add_u32 %2," #C1 ",%2\n v_add_u32 %3," #C1 ",%3\n"                \
  "v_add3_u32 %0,%0,%4,%2\n v_add3_u32 %1,%1,%4,%3\n"                  \
  "v_alignbit_b32 %2,%2,%2," #S "\n v_alignbit_b32 %3,%3,%3," #S "\n"  \
  "v_xor_b32 %2,%2,%0\n v_xor_b32 %3,%3,%1\n"

#define TF_RINJ02(C1, S) \
  "v_add_u32 %2," #C1 ",%2\n v_add_u32 %3," #C1 ",%3\n"                \
  "v_add_u32 %0,%0,%2\n v_add_u32 %1,%1,%3\n"                          \
  "v_alignbit_b32 %2,%2,%2," #S "\n v_alignbit_b32 %3,%3,%3," #S "\n"  \
  "v_xor_b32 %2,%2,%0\n v_xor_b32 %3,%3,%1\n"

// t0 = ctr + 42, t1 = ctr + NK + 42
__device__ __forceinline__ void threefry2(uint32_t t0, uint32_t t1,
                                          uint32_t bits[2]) {
    uint32_t a0, a1, b0, b1;
    // round 1 (rot 13) with x0_init = 0:  x0 = t, x1 = rotl(t,13) ^ t
    a0 = t0; b0 = rotl(t0, 13) ^ t0;
    a1 = t1; b1 = rotl(t1, 13) ^ t1;
    asm(
        TF_ROUND2(17) TF_ROUND2(6) TF_ROUND2(26)        // r2-r4  (rot 15,26,6)
        TF_RINJ2(42, 0x1BD11BF1, 15)                    // inj(ks1,ks2+1) + r5 (rot17)
        TF_ROUND2(3) TF_ROUND2(16) TF_ROUND2(8)         // r6-r8  (rot 29,16,24)
        TF_RINJS2(2, 19)                                // inj(ks2,2)    + r9 (rot13)
        TF_ROUND2(17) TF_ROUND2(6) TF_ROUND2(26)        // r10-r12 (rot 15,26,6)
        TF_RINJ02(45, 15)                               // inj(0,ks1+3)  + r13 (rot17)
        TF_ROUND2(3) TF_ROUND2(16) TF_ROUND2(8)         // r14-r16 (rot 29,16,24)
        TF_RINJ2(42, 0x1BD11BF4, 19)                    // inj(ks1,ks2+4)+ r17 (rot13)
        TF_ROUND2(17) TF_ROUND2(6) TF_ROUND2(26)        // r18-r20 (rot 15,26,6)
        : "+v"(a0), "+v"(a1), "+v"(b0), "+v"(b1)
        : "s"(0x1BD11BF0u));
    bits[0] = (a0 + 0x1BD11BF0u) ^ (b0 + 5u);
    bits[1] = (a1 + 0x1BD11BF0u) ^ (b1 + 5u);
}

__device__ __forceinline__ float fexp2(float x) {
#if __has_builtin(__builtin_amdgcn_exp2f)
    return __builtin_amdgcn_exp2f(x);
#else
    return __expf(0.6931471805599453f * x);
#endif
}

// packed f32 helpers (v_pk_* full-rate on CDNA, IEEE-identical per half)
#define PK_MUL(D, A, B) \
    asm("v_pk_mul_f32 %0,%1,%2" : "=v"(D) : "v"(A), "v"(B))
#define PK_FMA(ACC, A, B) \
    asm("v_pk_fma_f32 %0,%1,%2,%0" : "+v"(ACC) : "v"(A), "v"(B))

// ---------------- tiny projection: out[r][c] = x[r][:] . w[c][:] + b[c] --
__global__ void proj_kernel(const float* __restrict__ x,
                            const float* __restrict__ w,
                            const float* __restrict__ b,
                            float* __restrict__ out, int dout) {
    __shared__ __align__(16) float ws[8 * DIN];
    __shared__ float bs[8];
    const int tid = threadIdx.x;
    if (tid < dout * DIN) ws[tid] = w[tid];
    if (tid < dout) bs[tid] = b[tid];
    __syncthreads();

    const int row = blockIdx.x * BT + tid;
    const float4* xr = reinterpret_cast<const float4*>(x + (size_t)row * DIN);
    float4 xv[8];
#pragma unroll
    for (int i = 0; i < 8; ++i) xv[i] = xr[i];

    for (int c = 0; c < dout; ++c) {
        float s = bs[c];
#pragma unroll
        for (int i = 0; i < 8; ++i) {
            const float4 wv = *reinterpret_cast<const float4*>(&ws[c * DIN + i * 4]);
            s += xv[i].x * wv.x + xv[i].y * wv.y + xv[i].z * wv.z + xv[i].w * wv.w;
        }
        out[(size_t)row * dout + c] = s;
    }
}

// ---------------- fused scores+softmax+dropout+PV (k-split partials) -----
// No LDS. k/v L2-resident, coalesced f32x2 loads. Compile-time ITERS +
// unroll-4: all inner load offsets fold into offset: immediates (k:
// 0/1024/2048/3072 B; v: 0/2048 B per pre-offset base), loop overhead and
// hash-counter setup amortize over 4 iterations.
template <int KSPLIT>
__global__
__attribute__((amdgpu_flat_work_group_size(BT, BT), amdgpu_waves_per_eu(8, 8)))
void attn_kernel(
    const float* __restrict__ q,        // [NQ][4] (projection output)
    const float* __restrict__ k,        // [NK][4]
    const float* __restrict__ v,        // [NK][8]
    float* __restrict__ partial) {      // [KSPLIT][NQ][12]: 8 nums, den
    constexpr int klen = NK / KSPLIT;
    constexpr int iters = klen / 64;    // 32 for KSPLIT=4 (multiple of 4)

    const int tid = threadIdx.x;
    const int lane = tid & 63;
    const int wave = tid >> 6;
    const int split = blockIdx.y;
    const int qbase = blockIdx.x * ROWS_PER_BLOCK + wave * RPW;
    const int kstart = split * klen;

    f32x2 q01[RPW], q23[RPW];
#pragma unroll
    for (int r = 0; r < RPW; ++r) {
        const float4 t = *reinterpret_cast<const float4*>(q + (size_t)(qbase + r) * 4);
        q01[r][0] = t.x * QSCALE; q01[r][1] = t.y * QSCALE;
        q23[r][0] = t.z * QSCALE; q23[r][1] = t.w * QSCALE;
    }

    f32x2 acc0[RPW], acc1[RPW], acc2[RPW], acc3[RPW];
    f32x2 denp = {0.f, 0.f};
#pragma unroll
    for (int r = 0; r < RPW; ++r) {
        acc0[r] = (f32x2){0.f, 0.f}; acc1[r] = (f32x2){0.f, 0.f};
        acc2[r] = (f32x2){0.f, 0.f}; acc3[r] = (f32x2){0.f, 0.f};
    }

    const f32x2* kp2  = reinterpret_cast<const f32x2*>(k) + 2 * (size_t)(kstart + lane);
    const f32x2* vp2a = reinterpret_cast<const f32x2*>(v) + 4 * (size_t)(kstart + lane);
    const f32x2* vp2b = vp2a + 512;     // +4096 B: covers unroll slots j=2,3
    const uint32_t ctr0 = (uint32_t)qbase * (uint32_t)NK + (uint32_t)(kstart + lane);
    uint32_t tb0 = ctr0 + 42u;          // chain j=0: ctr + ks1
    uint32_t tb1 = ctr0 + 8234u;        // chain j=1: ctr + NK + ks1

    for (int it = 0; it < iters; it += 4) {
#pragma unroll
        for (int j = 0; j < 4; ++j) {
            const f32x2* vp = (j < 2) ? vp2a : vp2b;
            const int jv = (j & 1) * 256;                 // 0 or 2048 B
            const f32x2 k01  = kp2[j * 128];              // 0/1024/2048/3072 B
            const f32x2 k23  = kp2[j * 128 + 1];
            const f32x2 va01 = vp[jv];
            const f32x2 va23 = vp[jv + 1];
            const f32x2 vb01 = vp[jv + 2];
            const f32x2 vb23 = vp[jv + 3];

            uint32_t bits[RPW];
            threefry2(tb0 + 64u * (uint32_t)j, tb1 + 64u * (uint32_t)j, bits);

            f32x2 ep;
#pragma unroll
            for (int r = 0; r < RPW; ++r) {
                f32x2 s01;
                PK_MUL(s01, q01[r], k01);
                PK_FMA(s01, q23[r], k23);
                ep[r] = fexp2(s01[0] + s01[1]);
            }
            denp += ep;
#pragma unroll
            for (int r = 0; r < RPW; ++r) {
                const float w = (bits[r] < KEEP_BITS) ? ep[r] : 0.0f;
                const f32x2 wp = {w, w};
                PK_FMA(acc0[r], va01, wp);
                PK_FMA(acc1[r], va23, wp);
                PK_FMA(acc2[r], vb01, wp);
                PK_FMA(acc3[r], vb23, wp);
            }
        }
        kp2  += 512;                    // 4 iters * 1024 B
        vp2a += 1024;                   // 4 iters * 2048 B
        vp2b += 1024;
        tb0 += 256u; tb1 += 256u;
    }

    // wave-level reduction of 9 accumulators per row, write partials
#pragma unroll
    for (int r = 0; r < RPW; ++r) {
        float n0 = acc0[r][0], n1 = acc0[r][1], n2 = acc1[r][0], n3 = acc1[r][1];
        float n4 = acc2[r][0], n5 = acc2[r][1], n6 = acc3[r][0], n7 = acc3[r][1];
        float dd = denp[r];
#pragma unroll
        for (int off = 32; off >= 1; off >>= 1) {
            n0 += __shfl_xor(n0, off); n1 += __shfl_xor(n1, off);
            n2 += __shfl_xor(n2, off); n3 += __shfl_xor(n3, off);
            n4 += __shfl_xor(n4, off); n5 += __shfl_xor(n5, off);
            n6 += __shfl_xor(n6, off); n7 += __shfl_xor(n7, off);
            dd += __shfl_xor(dd, off);
        }
        if (lane == 0) {
            float* p = partial + ((size_t)split * NQ + (size_t)(qbase + r)) * 12;
            p[0] = n0; p[1] = n1; p[2] = n2; p[3] = n3;
            p[4] = n4; p[5] = n5; p[6] = n6; p[7] = n7;
            p[8] = dd;
        }
    }
}

// ---------------- combine partials + final normalize ---------------------
__global__ void combine_kernel(const float* __restrict__ partial,
                               float* __restrict__ out, int ksplit) {
    const int row = blockIdx.x * 256 + threadIdx.x;
    float n[8] = {0.f, 0.f, 0.f, 0.f, 0.f, 0.f, 0.f, 0.f};
    float dd = 0.f;
    for (int s = 0; s < ksplit; ++s) {
        const float* p = partial + ((size_t)s * NQ + (size_t)row) * 12;
#pragma unroll
        for (int j = 0; j < 8; ++j) n[j] += p[j];
        dd += p[8];
    }
    const float inv = 1.0f / (0.8f * dd);
#pragma unroll
    for (int j = 0; j < 8; ++j) out[(size_t)row * 8 + j] = n[j] * inv;
}

extern "C" void kernel_launch(void* const* d_in, const int* in_sizes, int n_in,
                              void* d_out, int out_size, void* d_ws, size_t ws_size,
                              hipStream_t stream) {
    const float* x1   = (const float*)d_in[0];
    const float* x2   = (const float*)d_in[1];
    const float* wq_w = (const float*)d_in[2];
    const float* wq_b = (const float*)d_in[3];
    const float* wk_w = (const float*)d_in[4];
    const float* wk_b = (const float*)d_in[5];
    const float* wv_w = (const float*)d_in[6];
    const float* wv_b = (const float*)d_in[7];
    float* out = (float*)d_out;

    // workspace: q [8192*4] | k [8192*4] | v [8192*8] | partial [ksplit][8192][12]
    float* qws = (float*)d_ws;
    float* kws = qws + (size_t)NQ * 4;
    float* vws = kws + (size_t)NK * 4;
    float* pws = vws + (size_t)NK * 8;

    const size_t qkv_bytes = ((size_t)NQ * 4 + NK * 4 + NK * 8) * sizeof(float);
    const size_t per_split = (size_t)NQ * 12 * sizeof(float);
    int ksplit = 4;
    while (ksplit > 1 && ws_size < qkv_bytes + (size_t)ksplit * per_split) ksplit >>= 1;

    proj_kernel<<<NQ / BT, BT, 0, stream>>>(x1, wq_w, wq_b, qws, 4);
    proj_kernel<<<NK / BT, BT, 0, stream>>>(x2, wk_w, wk_b, kws, 4);
    proj_kernel<<<NK / BT, BT, 0, stream>>>(x2, wv_w, wv_b, vws, 8);

    dim3 grid(NQ / ROWS_PER_BLOCK, ksplit);
    if (ksplit == 4)      attn_kernel<4><<<grid, BT, 0, stream>>>(qws, kws, vws, pws);
    else if (ksplit == 2) attn_kernel<2><<<grid, BT, 0, stream>>>(qws, kws, vws, pws);
    else                  attn_kernel<1><<<grid, BT, 0, stream>>>(qws, kws, vws, pws);

    combine_kernel<<<NQ / 256, 256, 0, stream>>>(pws, out, ksplit);
}